// Round 8
// baseline (116.734 us; speedup 1.0000x reference)
//
#include <hip/hip_runtime.h>

// SKA: per-pixel dynamic depthwise 5x5 conv
// x: [B=8, C=256, H=64, W=64] f32
// w: [B=8, G=8, K2=25, H=64, W=64] f32
// out[b,c,h,w] = sum_k x[b,c,h+k/5-2,w+k%5-2] * w[b,g,k,h,w], g = c/32
//
// Design G (round 8): F2 + pair-unrolled channel loop.
// Round-7: passed, kernel dropped below the 42us harness fills (out of
// top-5). Remaining gap vs 16us traffic floor = per-iteration latency
// exposure (8 short iters, vmcnt wait covered by only ~450cyc of work,
// 2 loads in flight). This round: 2 channels per iteration ->
//  - 4 latency events instead of 8, each covered by ~2x the work
//  - 4 float4 loads in flight per wave instead of 2
//  - buf0=even ch, buf1=odd ch, both written+read each iter; buffer reuse
//    across iters still ordered by the wave_barrier pair.
// Proven pieces kept verbatim: pitch-66 LDS (4 accesses/bank = conflict
// floor), wave_barrier scheduling fences (zero-instruction, no vmcnt
// drain), masked-weight boundary handling, static indexing (SROA lesson),
// __launch_bounds__(256,2). Tripwire: WRITE_SIZE must stay 32768 KB.

#define B_ 8
#define C_ 256
#define G_ 8
#define CG_ 32
#define H_ 64
#define W_ 64
#define K2_ 25
#define HW_ (H_ * W_)
#define NCH 8      // channels per block
#define PITCH 66   // padded LDS row pitch in words (conflict-free)
#define BUFW 544   // words per buffer: 2 guard + 8*66 = 530, rounded up
#define WAVEW (2 * BUFW)

__global__ __launch_bounds__(256, 2) void ska_kernel(
    const float* __restrict__ x, const float* __restrict__ w,
    float* __restrict__ out) {
  __shared__ float lds[4 * WAVEW];
  const int tid = threadIdx.x;
  const int lane = tid & 63;
  const int wv = tid >> 6;
  const int j = lane & 15;  // column quad: cols 4j..4j+3
  const int r = lane >> 4;  // row within wave tile (0..3)
  const int blk = blockIdx.x;  // 1024 blocks
  const int chunk = blk & 3;
  const int band = (blk >> 2) & 3;
  const int g = (blk >> 4) & 7;
  const int b = blk >> 7;
  const int h0w = band * 16 + wv * 4;  // wave's first output row
  const int h = h0w + r;
  const int wcol = j * 4;
  const int wbase = wv * WAVEW;

  // ---- zero guards (words 0,1) + row pads (2+rr*66+{64,65}) of both bufs ----
  if (lane < 18) {
    int idx;
    if (lane < 2) idx = lane;
    else idx = 2 + ((lane - 2) >> 1) * PITCH + 64 + ((lane - 2) & 1);
    lds[wbase + idx] = 0.0f;
    lds[wbase + BUFW + idx] = 0.0f;
  }

  // ---- 25 per-pixel weight quads, OOB masks folded in (branch-free) ----
  float wk[K2_][4];
  const float* wb =
      w + (size_t)(b * G_ + g) * K2_ * HW_ + (size_t)h * W_ + wcol;
#pragma unroll
  for (int k = 0; k < K2_; ++k) {
    const int di = k / 5 - 2;
    const int dj = k % 5 - 2;
    const int hh = h + di;
    const bool rowok = (unsigned)hh < (unsigned)H_;
    const float4 wq = *(const float4*)(wb + (size_t)k * HW_);
#pragma unroll
    for (int t = 0; t < 4; ++t) {
      const int cc = wcol + t + dj;
      const bool ok = rowok && ((unsigned)cc < (unsigned)W_);
      wk[k][t] = ok ? ((const float*)&wq)[t] : 0.0f;
    }
  }

  // ---- staging constants: lane -> (window rows sr, sr+4; col quad scol) ----
  const int scol = (lane & 15) * 4;
  const int sr = lane >> 4;  // 0..3
  const int srow0 = min(max(h0w - 2 + sr, 0), H_ - 1);
  const int srow1 = min(max(h0w + 2 + sr, 0), H_ - 1);
  const int woff0 = wbase + 2 + sr * PITCH + scol;
  const int woff1 = wbase + 2 + (4 + sr) * PITCH + scol;

  const size_t chan0 = (size_t)(b * C_ + g * CG_ + chunk * NCH) * HW_;
  const float* xc = x + chan0;
  float* ob = out + chan0 + (size_t)h * W_ + wcol;

  // ---- prime: channels 0,1 windows in VGPRs ----
  float4 qa = *(const float4*)(xc + srow0 * W_ + scol);
  float4 qb = *(const float4*)(xc + srow1 * W_ + scol);
  float4 qc = *(const float4*)(xc + HW_ + srow0 * W_ + scol);
  float4 qd = *(const float4*)(xc + HW_ + srow1 * W_ + scol);

#pragma unroll
  for (int it = 0; it < 4; ++it) {
    const int c0 = 2 * it;
    // issue next pair's 4 loads (stay in flight across this iter's work);
    // last iter re-loads pair (6,7) harmlessly (clamped, stays in bounds)
    const int cnb = min(c0 + 2, NCH - 2);
    const float* xn = xc + (size_t)cnb * HW_;
    const float4 pa = *(const float4*)(xn + srow0 * W_ + scol);
    const float4 pb = *(const float4*)(xn + srow1 * W_ + scol);
    const float4 pc = *(const float4*)(xn + HW_ + srow0 * W_ + scol);
    const float4 pd = *(const float4*)(xn + HW_ + srow1 * W_ + scol);

    // pin order vs previous iteration's reads (buffer reuse)
    __builtin_amdgcn_wave_barrier();
    // even channel -> buf0, odd channel -> buf1
    *(float2*)&lds[woff0] = make_float2(qa.x, qa.y);
    *(float2*)&lds[woff0 + 2] = make_float2(qa.z, qa.w);
    *(float2*)&lds[woff1] = make_float2(qb.x, qb.y);
    *(float2*)&lds[woff1 + 2] = make_float2(qb.z, qb.w);
    *(float2*)&lds[woff0 + BUFW] = make_float2(qc.x, qc.y);
    *(float2*)&lds[woff0 + BUFW + 2] = make_float2(qc.z, qc.w);
    *(float2*)&lds[woff1 + BUFW] = make_float2(qd.x, qd.y);
    *(float2*)&lds[woff1 + BUFW + 2] = make_float2(qd.z, qd.w);
    // reads below must not be hoisted above the writes
    __builtin_amdgcn_wave_barrier();

#pragma unroll
    for (int u = 0; u < 2; ++u) {
      const int bo = u * BUFW;
      alignas(16) float acc[4] = {0.f, 0.f, 0.f, 0.f};
#pragma unroll
      for (int di = 0; di < 5; ++di) {
        // window row r+di, cols wcol-2..wcol+5 (guards/pads cover edges)
        const int base = wbase + bo + (r + di) * PITCH + wcol;  // data -2 off
        alignas(16) float xr[8];
        *(float2*)&xr[0] = *(const float2*)&lds[base];
        *(float2*)&xr[2] = *(const float2*)&lds[base + 2];
        *(float2*)&xr[4] = *(const float2*)&lds[base + 4];
        *(float2*)&xr[6] = *(const float2*)&lds[base + 6];
#pragma unroll
        for (int dj = 0; dj < 5; ++dj) {
          const int k = di * 5 + dj;
#pragma unroll
          for (int t = 0; t < 4; ++t) {
            acc[t] = fmaf(xr[t + dj], wk[k][t], acc[t]);
          }
        }
      }
      *(float4*)(ob + (size_t)(c0 + u) * HW_) = *(const float4*)acc;
    }
    qa = pa;
    qb = pb;
    qc = pc;
    qd = pd;
  }
}

extern "C" void kernel_launch(void* const* d_in, const int* in_sizes, int n_in,
                              void* d_out, int out_size, void* d_ws,
                              size_t ws_size, hipStream_t stream) {
  const float* x = (const float*)d_in[0];
  const float* w = (const float*)d_in[1];
  float* out = (float*)d_out;
  // grid: B*G * 4 bands * 4 channel-chunks = 1024 blocks of 256 threads
  ska_kernel<<<dim3(1024), dim3(256), 0, stream>>>(x, w, out);
}